// Round 7
// baseline (305.850 us; speedup 1.0000x reference)
//
#include <hip/hip_runtime.h>
#include <math.h>

#define HH 1024
#define SS 1024
#define EE 3

typedef __bf16 bf16x8 __attribute__((ext_vector_type(8)));
typedef float floatx4 __attribute__((ext_vector_type(4)));

__device__ __forceinline__ unsigned short f2bf(float f) {
  union { float f; unsigned u; } v; v.f = f;
  unsigned r = 0x7FFFu + ((v.u >> 16) & 1u);
  return (unsigned short)((v.u + r) >> 16);
}
__device__ __forceinline__ unsigned pack2(float lo, float hi) {
#if __has_builtin(__builtin_amdgcn_cvt_pk_bf16_f32)
  auto p = __builtin_amdgcn_cvt_pk_bf16_f32(lo, hi);
  return __builtin_bit_cast(unsigned, p);
#else
  return ((unsigned)f2bf(hi) << 16) | (unsigned)f2bf(lo);
#endif
}

#define GLDS(gp, lp)                                                    \
  __builtin_amdgcn_global_load_lds(                                     \
      (const __attribute__((address_space(1))) void*)(const void*)(gp), \
      (__attribute__((address_space(3))) void*)(void*)(lp), 16, 0, 0)

// ---- kernel 1: routing (argmax + gate) fused with x -> bf16, plus We ----
// ---- fp32->bf16 conversion riding along in blocks >= 1536 (independent) ----
__global__ __launch_bounds__(256) void k_route(
    const float* __restrict__ x,          // [B,3,S,H] fp32
    const float* __restrict__ wg,         // [3,H,3]   fp32
    const float* __restrict__ We,         // [3,E,H,H] fp32
    unsigned short* __restrict__ xb,      // [3,T,H] bf16 out
    unsigned short* __restrict__ wbuf,    // [9,H,H] bf16 out
    int* __restrict__ idx_out,            // [3*T]
    float* __restrict__ gv_out,           // [3*T]
    int T) {
  if (blockIdx.x >= 1536) {
    // ---- convw part: 1152 blocks x 256 threads x 4 segments of 8 elems ----
    int b = blockIdx.x - 1536;
    int base = b * 1024 + threadIdx.x;
#pragma unroll
    for (int k = 0; k < 4; ++k) {
      int i = base + k * 256;  // < 1152*1024 = 9*HH*HH/8 exactly
      const float4* p = reinterpret_cast<const float4*>(We + (size_t)i * 8);
      float4 a = p[0], bv = p[1];
      uint4 pk;
      pk.x = pack2(a.x, a.y);  pk.y = pack2(a.z, a.w);
      pk.z = pack2(bv.x, bv.y); pk.w = pack2(bv.z, bv.w);
      *reinterpret_cast<uint4*>(wbuf + (size_t)i * 8) = pk;
    }
    return;
  }
  int gw = (blockIdx.x * 256 + threadIdx.x) >> 6;  // global wave id [0,6144)
  int lane = threadIdx.x & 63;
  int r = gw >> 11;          // branch [0,3)
  int t0 = gw & 2047;        // starting token
  const float* w = wg + (size_t)r * HH * EE;

  // hoist this lane's gate slice: chunks c=0,1; h0 = c*512 + lane*8
  float wreg[2][24];
#pragma unroll
  for (int c = 0; c < 2; ++c) {
    int h0 = c * 512 + lane * 8;
    const float4* wp = reinterpret_cast<const float4*>(w + (size_t)h0 * 3);
#pragma unroll
    for (int j = 0; j < 6; ++j)
      *reinterpret_cast<float4*>(&wreg[c][4 * j]) = wp[j];
  }

  for (int t = t0; t < T; t += 2048) {
    const float* xrow =
        x + (size_t)(((t >> 10) * 3 + r) * SS + (t & 1023)) * HH;
    unsigned short* xbrow = xb + (size_t)(r * T + t) * HH;
    double a0 = 0, a1 = 0, a2 = 0;
#pragma unroll
    for (int c = 0; c < 2; ++c) {
      int h0 = c * 512 + lane * 8;
      float4 xa = *reinterpret_cast<const float4*>(xrow + h0);
      float4 xb4 = *reinterpret_cast<const float4*>(xrow + h0 + 4);
      float xs[8] = {xa.x, xa.y, xa.z, xa.w, xb4.x, xb4.y, xb4.z, xb4.w};
      // fused bf16 write-out (RNE, same as GEMM previously used)
      uint4 pk;
      pk.x = pack2(xs[0], xs[1]); pk.y = pack2(xs[2], xs[3]);
      pk.z = pack2(xs[4], xs[5]); pk.w = pack2(xs[6], xs[7]);
      *reinterpret_cast<uint4*>(xbrow + h0) = pk;
#pragma unroll
      for (int j = 0; j < 8; ++j) {
        double xv = (double)xs[j];
        a0 += xv * (double)wreg[c][3 * j + 0];
        a1 += xv * (double)wreg[c][3 * j + 1];
        a2 += xv * (double)wreg[c][3 * j + 2];
      }
    }
#pragma unroll
    for (int d = 32; d >= 1; d >>= 1) {
      a0 += __shfl_xor(a0, d, 64);
      a1 += __shfl_xor(a1, d, 64);
      a2 += __shfl_xor(a2, d, 64);
    }
    if (lane == 0) {
      int best = 0; double bl = a0;
      if (a1 > bl) { best = 1; bl = a1; }  // strict >: first-max wins
      if (a2 > bl) { best = 2; bl = a2; }
      float g = 1.0f / (expf((float)(a0 - bl)) + expf((float)(a1 - bl)) +
                        expf((float)(a2 - bl)));
      idx_out[r * T + t] = best;
      gv_out[r * T + t] = g;
    }
  }
}

// ---------------- kernel 2: arrival-order scan + expert lists ----------------
__global__ __launch_bounds__(1024) void k_scan(
    const int* __restrict__ idx, const float* __restrict__ gv,
    int* __restrict__ perm,    // [3*3*T] token ids per (branch,expert)
    float* __restrict__ scale, // [3*T]  gate*keep (0 if dropped)
    int* __restrict__ counts,  // [9]
    int T, int C) {
  int r = blockIdx.x;
  int tid = threadIdx.x;
  int per = T >> 10;  // tokens per thread (T=8192 -> 8)
  int t0 = tid * per;
  const int* idxr = idx + (size_t)r * T;

  int c0 = 0, c1 = 0, c2 = 0;
  for (int k = 0; k < per; ++k) {
    int e = idxr[t0 + k];
    c0 += (e == 0); c1 += (e == 1); c2 += (e == 2);
  }
  int lane = tid & 63, wv = tid >> 6;
  int s0 = c0, s1 = c1, s2 = c2;  // wave inclusive scan
  for (int d = 1; d < 64; d <<= 1) {
    int u0 = __shfl_up(s0, d, 64);
    int u1 = __shfl_up(s1, d, 64);
    int u2 = __shfl_up(s2, d, 64);
    if (lane >= d) { s0 += u0; s1 += u1; s2 += u2; }
  }
  __shared__ int wsum[16][3];
  __shared__ int wbase[16][3];
  if (lane == 63) { wsum[wv][0] = s0; wsum[wv][1] = s1; wsum[wv][2] = s2; }
  __syncthreads();
  if (tid == 0) {
    int b0 = 0, b1 = 0, b2 = 0;
    int nw = blockDim.x >> 6;
    for (int i = 0; i < nw; ++i) {
      wbase[i][0] = b0; wbase[i][1] = b1; wbase[i][2] = b2;
      b0 += wsum[i][0]; b1 += wsum[i][1]; b2 += wsum[i][2];
    }
    counts[r * 3 + 0] = b0; counts[r * 3 + 1] = b1; counts[r * 3 + 2] = b2;
  }
  __syncthreads();
  int off[3];
  off[0] = wbase[wv][0] + s0 - c0;
  off[1] = wbase[wv][1] + s1 - c1;
  off[2] = wbase[wv][2] + s2 - c2;
  for (int k = 0; k < per; ++k) {
    int e = idxr[t0 + k];
    int p = off[e]++;
    perm[(size_t)(r * 3 + e) * T + p] = t0 + k;
    scale[(size_t)r * T + t0 + k] = (p < C) ? gv[(size_t)r * T + t0 + k] : 0.0f;
  }
}

// ---- kernel 3: grouped GEMM, 2-phase 256x256, BK=64, 8 waves, dbuf ----
// Catalog datum (m248v2/m230, refcheck'd, grouped @K=1024): 2-phase 256^2 =
// 655-682 TF vs our R4 518. Mechanism: per-tile drain cost is ~fixed; BK=64
// amortizes it over 64 MFMA (R4: 16, R5's BK=32 lockstep: 32).
// ALL addressing is R5-verbatim (R5 passed correctness): BK=64 stored as TWO
// independent 256x32 k-half regions, so R5's write rotation (sseg) + read
// slot (rslot, 0 conflicts measured) + 8-wave acc[8][4] epilogue carry over
// unchanged. Dbuf race proof: compute reads buf (t&1) while STAGE writes
// buf (t+1)&1 (disjoint); __syncthreads() per tile drains vmcnt (compiler
// semantics) so the next buffer is landed, and orders read-before-overwrite.
__global__ __launch_bounds__(512, 2) void k_gemm(
    const unsigned short* __restrict__ xb,  // [3,T,H] bf16
    const unsigned short* __restrict__ wb,  // [3,3,H,H] bf16 (W[o][h])
    const float* __restrict__ be,           // [3,3,H] fp32
    const int* __restrict__ perm, const float* __restrict__ scale,
    const int* __restrict__ counts,
    float* __restrict__ out,                // [B,3,S,H] fp32
    int T) {
  // XCD chunking (bijective: 1152 = 8*144), n-fastest so the 4 n-siblings
  // sharing one gathered A panel land on the same XCD (R4-verified FETCH/2).
  int p = blockIdx.x;                 // 0..1151
  int wg = (p & 7) * 144 + (p >> 3);
  int z = wg >> 7;                    // 0..8 (branch*3 + expert)
  int rem = wg & 127;
  int x = rem >> 2;                   // m-block 0..31
  int y = rem & 3;                    // n-block 0..3

  int r = z / 3;
  int count = counts[z];
  int m0 = x * 256;
  if (m0 >= count) return;
  int n0 = y * 256;

  __shared__ alignas(16) unsigned short As[2][2][256 * 32];  // [buf][khalf]
  __shared__ alignas(16) unsigned short Bs[2][2][256 * 32];  // 128 KB total
  __shared__ int toks[256];
  __shared__ float scl[256];
  __shared__ float bias_s[256];

  int tid = threadIdx.x;
  int lane = tid & 63;
  int w = tid >> 6;     // wave 0..7

  if (tid < 256) {
    int row = m0 + tid;
    int grow = row < count ? row : count - 1;  // clamp (valid addr, store-guarded)
    int tok = perm[(size_t)z * T + grow];
    toks[tid] = tok;
    scl[tid] = (row < count) ? scale[(size_t)r * T + tok] : 0.0f;
    bias_s[tid] = be[(size_t)z * HH + n0 + tid];
  }
  __syncthreads();  // toks ready for aoff computation

  // staging (R5-verbatim): GLDS linear: lane l -> row base+(l>>2), 16B slot
  // l&3 within a 256x32 region. Write rotation: LDS slot j of row R holds
  // global segment (j - ((R>>1)&3))&3, applied by pre-rotating the per-lane
  // GLOBAL source offset (rule 21). (l>>3)&3 == ((R&15)>>1)&3 for base%16==0.
  size_t aoff[2], boff[2];
  int sseg = ((lane & 3) - ((lane >> 3) & 3)) & 3;
#pragma unroll
  for (int c = 0; c < 2; ++c) {
    int rowl = c * 128 + w * 16 + (lane >> 2);
    int tok = toks[rowl];
    aoff[c] = (size_t)(r * T + tok) * HH + sseg * 8;
    boff[c] = ((size_t)z * HH + n0 + rowl) * HH + sseg * 8;  // W[n][h]
  }

  int wr = w >> 2;        // 0..1 -> m-offset wr*128
  int wc = w & 3;         // 0..3 -> n-offset wc*64
  int wm = wr * 128;
  int wn = wc * 64;
  floatx4 acc[8][4] = {};

  // read side (R5-verbatim, measured 0 conflicts): frag row = base16 + rl;
  // slot = (q + ((rl>>1)&3))&3, q = lane>>4.
  int rl = lane & 15;
  int rslot = (((lane >> 4) + ((rl >> 1) & 3)) & 3) * 8;  // elem offset in row

  // STAGE one K-tile (64 k-elems = 2 k-half regions) into buf t&1: 8 GLDS.
  auto STAGE = [&](int t) {
    int b_ = t & 1;
    size_t kk = (size_t)t * 64;
#pragma unroll
    for (int h = 0; h < 2; ++h) {
#pragma unroll
      for (int c = 0; c < 2; ++c) {
        GLDS(xb + aoff[c] + kk + h * 32, &As[b_][h][(c * 128 + w * 16) * 32]);
        GLDS(wb + boff[c] + kk + h * 32, &Bs[b_][h][(c * 128 + w * 16) * 32]);
      }
    }
  };
  auto COMPUTE = [&](int t) {
    int b_ = t & 1;
#pragma unroll
    for (int ks = 0; ks < 2; ++ks) {
      const unsigned short* Ar = As[b_][ks];
      const unsigned short* Br = Bs[b_][ks];
      bf16x8 af[8], bq[4];
#pragma unroll
      for (int mt = 0; mt < 8; ++mt)
        af[mt] = *reinterpret_cast<const bf16x8*>(
            &Ar[(wm + mt * 16 + rl) * 32 + rslot]);
#pragma unroll
      for (int nt = 0; nt < 4; ++nt)
        bq[nt] = *reinterpret_cast<const bf16x8*>(
            &Br[(wn + nt * 16 + rl) * 32 + rslot]);
      __builtin_amdgcn_s_setprio(1);
#pragma unroll
      for (int mt = 0; mt < 8; ++mt)
#pragma unroll
        for (int nt = 0; nt < 4; ++nt)
          acc[mt][nt] = __builtin_amdgcn_mfma_f32_16x16x32_bf16(
              af[mt], bq[nt], acc[mt][nt], 0, 0, 0);
      __builtin_amdgcn_s_setprio(0);
    }
  };

  STAGE(0);
  __syncthreads();  // drains vmcnt: tile 0 landed
  for (int t = 0; t < 16; ++t) {   // K = 1024 -> 16 tiles of 64
    if (t < 15) STAGE(t + 1);      // prefetch into the other buffer
    COMPUTE(t);                    // 64 MFMA over this buffer
    __syncthreads();               // drain prefetch + order buffer swap
  }

  // epilogue (R5-verbatim): D row = (lane>>4)*4+reg, col = lane&15
#pragma unroll
  for (int mt = 0; mt < 8; ++mt) {
#pragma unroll
    for (int rr = 0; rr < 4; ++rr) {
      int ml = wm + mt * 16 + (lane >> 4) * 4 + rr;
      if (m0 + ml < count) {
        float sc = scl[ml];
        int tok = toks[ml];
        size_t ob =
            (size_t)(((tok >> 10) * 3 + r) * SS + (tok & 1023)) * HH + n0;
#pragma unroll
        for (int nt = 0; nt < 4; ++nt) {
          int nl = wn + nt * 16 + rl;
          out[ob + nl] = sc * (acc[mt][nt][rr] + bias_s[nl]);
        }
      }
    }
  }
}

extern "C" void kernel_launch(void* const* d_in, const int* in_sizes, int n_in,
                              void* d_out, int out_size, void* d_ws,
                              size_t ws_size, hipStream_t stream) {
  const float* feat = (const float*)d_in[0];  // features fp32
  const float* gw   = (const float*)d_in[1];  // gate_w fp32
  const float* ew   = (const float*)d_in[2];  // expert_w fp32
  const float* eb   = (const float*)d_in[3];  // expert_b fp32
  float* out = (float*)d_out;

  int B = in_sizes[0] / (3 * SS * HH);
  int T = B * SS;                  // tokens per branch (8192)
  int C = (T + EE - 1) / EE;       // capacity = ceil(T/E) = 2731

  // workspace layout: xb bf16 [3,T,H] | wb bf16 [9,H,H] | ints/floats (~70 MB)
  unsigned short* xbuf = (unsigned short*)d_ws;           // 3*T*HH shorts
  unsigned short* wbuf = xbuf + (size_t)3 * T * HH;       // 9*HH*HH shorts
  int* perm   = (int*)(wbuf + (size_t)9 * HH * HH);       // 9*T
  int* counts = perm + (size_t)9 * T;                     // 16 (padded)
  int* idxb   = counts + 16;                              // 3*T
  float* gv   = (float*)(idxb + (size_t)3 * T);           // 3*T
  float* scl  = gv + (size_t)3 * T;                       // 3*T

  // route (1536 blocks) + weight conversion (1152 blocks) in one launch
  k_route<<<dim3(2688), dim3(256), 0, stream>>>(feat, gw, ew, xbuf, wbuf,
                                                idxb, gv, T);
  k_scan<<<dim3(3), dim3(1024), 0, stream>>>(idxb, gv, perm, scl, counts, T, C);
  k_gemm<<<dim3(1152), dim3(512), 0, stream>>>(
      xbuf, wbuf, eb, perm, scl, counts, out, T);
}

// Round 8
// 290.630 us; speedup vs baseline: 1.0524x; 1.0524x over previous
//
#include <hip/hip_runtime.h>
#include <math.h>

#define HH 1024
#define SS 1024
#define EE 3

typedef __bf16 bf16x8 __attribute__((ext_vector_type(8)));
typedef float floatx4 __attribute__((ext_vector_type(4)));

__device__ __forceinline__ unsigned short f2bf(float f) {
  union { float f; unsigned u; } v; v.f = f;
  unsigned r = 0x7FFFu + ((v.u >> 16) & 1u);
  return (unsigned short)((v.u + r) >> 16);
}
__device__ __forceinline__ unsigned pack2(float lo, float hi) {
#if __has_builtin(__builtin_amdgcn_cvt_pk_bf16_f32)
  auto p = __builtin_amdgcn_cvt_pk_bf16_f32(lo, hi);
  return __builtin_bit_cast(unsigned, p);
#else
  return ((unsigned)f2bf(hi) << 16) | (unsigned)f2bf(lo);
#endif
}

#define GLDS(gp, lp)                                                    \
  __builtin_amdgcn_global_load_lds(                                     \
      (const __attribute__((address_space(1))) void*)(const void*)(gp), \
      (__attribute__((address_space(3))) void*)(void*)(lp), 16, 0, 0)

// ---- kernel 1: routing (argmax + gate) fused with x -> bf16, plus We ----
// ---- fp32->bf16 conversion riding along in blocks >= 1536 (independent) ----
__global__ __launch_bounds__(256) void k_route(
    const float* __restrict__ x,          // [B,3,S,H] fp32
    const float* __restrict__ wg,         // [3,H,3]   fp32
    const float* __restrict__ We,         // [3,E,H,H] fp32
    unsigned short* __restrict__ xb,      // [3,T,H] bf16 out
    unsigned short* __restrict__ wbuf,    // [9,H,H] bf16 out
    int* __restrict__ idx_out,            // [3*T]
    float* __restrict__ gv_out,           // [3*T]
    int T) {
  if (blockIdx.x >= 1536) {
    // ---- convw part: 1152 blocks x 256 threads x 4 segments of 8 elems ----
    int b = blockIdx.x - 1536;
    int base = b * 1024 + threadIdx.x;
#pragma unroll
    for (int k = 0; k < 4; ++k) {
      int i = base + k * 256;  // < 1152*1024 = 9*HH*HH/8 exactly
      const float4* p = reinterpret_cast<const float4*>(We + (size_t)i * 8);
      float4 a = p[0], bv = p[1];
      uint4 pk;
      pk.x = pack2(a.x, a.y);  pk.y = pack2(a.z, a.w);
      pk.z = pack2(bv.x, bv.y); pk.w = pack2(bv.z, bv.w);
      *reinterpret_cast<uint4*>(wbuf + (size_t)i * 8) = pk;
    }
    return;
  }
  int gw = (blockIdx.x * 256 + threadIdx.x) >> 6;  // global wave id [0,6144)
  int lane = threadIdx.x & 63;
  int r = gw >> 11;          // branch [0,3)
  int t0 = gw & 2047;        // starting token
  const float* w = wg + (size_t)r * HH * EE;

  // hoist this lane's gate slice: chunks c=0,1; h0 = c*512 + lane*8
  float wreg[2][24];
#pragma unroll
  for (int c = 0; c < 2; ++c) {
    int h0 = c * 512 + lane * 8;
    const float4* wp = reinterpret_cast<const float4*>(w + (size_t)h0 * 3);
#pragma unroll
    for (int j = 0; j < 6; ++j)
      *reinterpret_cast<float4*>(&wreg[c][4 * j]) = wp[j];
  }

  for (int t = t0; t < T; t += 2048) {
    const float* xrow =
        x + (size_t)(((t >> 10) * 3 + r) * SS + (t & 1023)) * HH;
    unsigned short* xbrow = xb + (size_t)(r * T + t) * HH;
    double a0 = 0, a1 = 0, a2 = 0;
#pragma unroll
    for (int c = 0; c < 2; ++c) {
      int h0 = c * 512 + lane * 8;
      float4 xa = *reinterpret_cast<const float4*>(xrow + h0);
      float4 xb4 = *reinterpret_cast<const float4*>(xrow + h0 + 4);
      float xs[8] = {xa.x, xa.y, xa.z, xa.w, xb4.x, xb4.y, xb4.z, xb4.w};
      // fused bf16 write-out (RNE, same as GEMM previously used)
      uint4 pk;
      pk.x = pack2(xs[0], xs[1]); pk.y = pack2(xs[2], xs[3]);
      pk.z = pack2(xs[4], xs[5]); pk.w = pack2(xs[6], xs[7]);
      *reinterpret_cast<uint4*>(xbrow + h0) = pk;
#pragma unroll
      for (int j = 0; j < 8; ++j) {
        double xv = (double)xs[j];
        a0 += xv * (double)wreg[c][3 * j + 0];
        a1 += xv * (double)wreg[c][3 * j + 1];
        a2 += xv * (double)wreg[c][3 * j + 2];
      }
    }
#pragma unroll
    for (int d = 32; d >= 1; d >>= 1) {
      a0 += __shfl_xor(a0, d, 64);
      a1 += __shfl_xor(a1, d, 64);
      a2 += __shfl_xor(a2, d, 64);
    }
    if (lane == 0) {
      int best = 0; double bl = a0;
      if (a1 > bl) { best = 1; bl = a1; }  // strict >: first-max wins
      if (a2 > bl) { best = 2; bl = a2; }
      float g = 1.0f / (expf((float)(a0 - bl)) + expf((float)(a1 - bl)) +
                        expf((float)(a2 - bl)));
      idx_out[r * T + t] = best;
      gv_out[r * T + t] = g;
    }
  }
}

// ---------------- kernel 2: arrival-order scan + expert lists ----------------
__global__ __launch_bounds__(1024) void k_scan(
    const int* __restrict__ idx, const float* __restrict__ gv,
    int* __restrict__ perm,    // [3*3*T] token ids per (branch,expert)
    float* __restrict__ scale, // [3*T]  gate*keep (0 if dropped)
    int* __restrict__ counts,  // [9]
    int T, int C) {
  int r = blockIdx.x;
  int tid = threadIdx.x;
  int per = T >> 10;  // tokens per thread (T=8192 -> 8)
  int t0 = tid * per;
  const int* idxr = idx + (size_t)r * T;

  int c0 = 0, c1 = 0, c2 = 0;
  for (int k = 0; k < per; ++k) {
    int e = idxr[t0 + k];
    c0 += (e == 0); c1 += (e == 1); c2 += (e == 2);
  }
  int lane = tid & 63, wv = tid >> 6;
  int s0 = c0, s1 = c1, s2 = c2;  // wave inclusive scan
  for (int d = 1; d < 64; d <<= 1) {
    int u0 = __shfl_up(s0, d, 64);
    int u1 = __shfl_up(s1, d, 64);
    int u2 = __shfl_up(s2, d, 64);
    if (lane >= d) { s0 += u0; s1 += u1; s2 += u2; }
  }
  __shared__ int wsum[16][3];
  __shared__ int wbase[16][3];
  if (lane == 63) { wsum[wv][0] = s0; wsum[wv][1] = s1; wsum[wv][2] = s2; }
  __syncthreads();
  if (tid == 0) {
    int b0 = 0, b1 = 0, b2 = 0;
    int nw = blockDim.x >> 6;
    for (int i = 0; i < nw; ++i) {
      wbase[i][0] = b0; wbase[i][1] = b1; wbase[i][2] = b2;
      b0 += wsum[i][0]; b1 += wsum[i][1]; b2 += wsum[i][2];
    }
    counts[r * 3 + 0] = b0; counts[r * 3 + 1] = b1; counts[r * 3 + 2] = b2;
  }
  __syncthreads();
  int off[3];
  off[0] = wbase[wv][0] + s0 - c0;
  off[1] = wbase[wv][1] + s1 - c1;
  off[2] = wbase[wv][2] + s2 - c2;
  for (int k = 0; k < per; ++k) {
    int e = idxr[t0 + k];
    int p = off[e]++;
    perm[(size_t)(r * 3 + e) * T + p] = t0 + k;
    scale[(size_t)r * T + t0 + k] = (p < C) ? gv[(size_t)r * T + t0 + k] : 0.0f;
  }
}

// ---- kernel 3: grouped GEMM, 256x256 BK=64 dbuf + COUNTED 2-phase/tile ----
// R7 (identical geometry, __syncthreads-drained) = 98.8us, MfmaUtil 21%.
// m218 isolated the mechanism we're missing: within a phase-split schedule,
// counted-vmcnt vs drain-to-0 = +38-73%. This round changes ONLY the K-loop
// schedule; addressing/swizzle/epilogue are R7-byte-identical (verified).
//
// Per K-tile t: two phases (ks=0/1). STAGE(t+1) split into chunk01
// (A-h0,B-h0; 4 GLDS) issued in phase 1 and chunk23 (A-h1,B-h1) in phase 2.
// Each phase opens with fused "s_waitcnt vmcnt(4); s_barrier" -> the GLDS
// queue NEVER drains below 4 in the main loop.
// Induction (per-wave, in-order retirement):
//   entering P1(t): outstanding <= 8 = {chunk23(t), chunk01(t+1)}... wait(4)
//   retires the OLDER 4 = exactly the ks=0 regions P1 reads; barrier -> all
//   waves' shares landed. P2(t)'s wait(4) retires chunk23(t) = ks=1 regions.
// WAR safety: GLDS(t+1) writes buf cur^1, last read in tile t-1; each wave's
// t-1 reads complete before its own MFMA (compiler lgkm) which precedes
// P1(t)'s barrier -> no wave issues t+1 GLDS until all t-1 reads retired.
// Tail: t=15 stages nothing; P2 opens with vmcnt(0) (full drain, last tile).
__global__ __launch_bounds__(512, 2) void k_gemm(
    const unsigned short* __restrict__ xb,  // [3,T,H] bf16
    const unsigned short* __restrict__ wb,  // [3,3,H,H] bf16 (W[o][h])
    const float* __restrict__ be,           // [3,3,H] fp32
    const int* __restrict__ perm, const float* __restrict__ scale,
    const int* __restrict__ counts,
    float* __restrict__ out,                // [B,3,S,H] fp32
    int T) {
  // XCD chunking (bijective: 1152 = 8*144), n-fastest so the 4 n-siblings
  // sharing one gathered A panel land on the same XCD (R4-verified FETCH/2).
  int p = blockIdx.x;                 // 0..1151
  int wg = (p & 7) * 144 + (p >> 3);
  int z = wg >> 7;                    // 0..8 (branch*3 + expert)
  int rem = wg & 127;
  int x = rem >> 2;                   // m-block 0..31
  int y = rem & 3;                    // n-block 0..3

  int r = z / 3;
  int count = counts[z];
  int m0 = x * 256;
  if (m0 >= count) return;
  int n0 = y * 256;

  __shared__ alignas(16) unsigned short As[2][2][256 * 32];  // [buf][khalf]
  __shared__ alignas(16) unsigned short Bs[2][2][256 * 32];  // 128 KB total
  __shared__ int toks[256];
  __shared__ float scl[256];
  __shared__ float bias_s[256];

  int tid = threadIdx.x;
  int lane = tid & 63;
  int w = tid >> 6;     // wave 0..7

  if (tid < 256) {
    int row = m0 + tid;
    int grow = row < count ? row : count - 1;  // clamp (valid addr, store-guarded)
    int tok = perm[(size_t)z * T + grow];
    toks[tid] = tok;
    scl[tid] = (row < count) ? scale[(size_t)r * T + tok] : 0.0f;
    bias_s[tid] = be[(size_t)z * HH + n0 + tid];
  }
  __syncthreads();  // toks ready; drains vmcnt -> pipeline counter starts at 0

  // staging (R7-verbatim): GLDS linear: lane l -> row base+(l>>2), 16B slot
  // l&3 within a 256x32 region. Write rotation: LDS slot j of row R holds
  // global segment (j - ((R>>1)&3))&3, applied by pre-rotating the per-lane
  // GLOBAL source offset (rule 21). (l>>3)&3 == ((R&15)>>1)&3 for base%16==0.
  size_t aoff[2], boff[2];
  int sseg = ((lane & 3) - ((lane >> 3) & 3)) & 3;
#pragma unroll
  for (int c = 0; c < 2; ++c) {
    int rowl = c * 128 + w * 16 + (lane >> 2);
    int tok = toks[rowl];
    aoff[c] = (size_t)(r * T + tok) * HH + sseg * 8;
    boff[c] = ((size_t)z * HH + n0 + rowl) * HH + sseg * 8;  // W[n][h]
  }

  int wr = w >> 2;        // 0..1 -> m-offset wr*128
  int wc = w & 3;         // 0..3 -> n-offset wc*64
  int wm = wr * 128;
  int wn = wc * 64;
  floatx4 acc[8][4] = {};

  // read side (R7-verbatim, measured 0 conflicts): frag row = base16 + rl;
  // slot = (q + ((rl>>1)&3))&3, q = lane>>4.
  int rl = lane & 15;
  int rslot = (((lane >> 4) + ((rl >> 1) & 3)) & 3) * 8;  // elem offset in row

  // chunk01: ks=0 regions (A-h0, B-h0) of buf t&1 -- 4 GLDS/wave
  auto STAGE01 = [&](int t) {
    int b_ = t & 1;
    size_t kk = (size_t)t * 64;
#pragma unroll
    for (int c = 0; c < 2; ++c) {
      GLDS(xb + aoff[c] + kk, &As[b_][0][(c * 128 + w * 16) * 32]);
      GLDS(wb + boff[c] + kk, &Bs[b_][0][(c * 128 + w * 16) * 32]);
    }
  };
  // chunk23: ks=1 regions (A-h1, B-h1) -- 4 GLDS/wave
  auto STAGE23 = [&](int t) {
    int b_ = t & 1;
    size_t kk = (size_t)t * 64 + 32;
#pragma unroll
    for (int c = 0; c < 2; ++c) {
      GLDS(xb + aoff[c] + kk, &As[b_][1][(c * 128 + w * 16) * 32]);
      GLDS(wb + boff[c] + kk, &Bs[b_][1][(c * 128 + w * 16) * 32]);
    }
  };
  // one phase: ds_read 12 frags of (buf t&1, khalf ks), issue next chunk,
  // 32 MFMA under setprio. Compiler inserts lgkm waits for af/bq deps.
  auto HALF = [&](int t, int ks, bool st) {
    const unsigned short* Ar = As[t & 1][ks];
    const unsigned short* Br = Bs[t & 1][ks];
    bf16x8 af[8], bq[4];
#pragma unroll
    for (int mt = 0; mt < 8; ++mt)
      af[mt] = *reinterpret_cast<const bf16x8*>(
          &Ar[(wm + mt * 16 + rl) * 32 + rslot]);
#pragma unroll
    for (int nt = 0; nt < 4; ++nt)
      bq[nt] = *reinterpret_cast<const bf16x8*>(
          &Br[(wn + nt * 16 + rl) * 32 + rslot]);
    if (st) {
      if (ks == 0) STAGE01(t + 1);
      else         STAGE23(t + 1);
    }
    __builtin_amdgcn_s_setprio(1);
#pragma unroll
    for (int mt = 0; mt < 8; ++mt)
#pragma unroll
      for (int nt = 0; nt < 4; ++nt)
        acc[mt][nt] = __builtin_amdgcn_mfma_f32_16x16x32_bf16(
            af[mt], bq[nt], acc[mt][nt], 0, 0, 0);
    __builtin_amdgcn_s_setprio(0);
  };

  STAGE01(0);
  STAGE23(0);
  for (int t = 0; t < 16; ++t) {   // K = 1024 -> 16 tiles of 64
    // phase 1 (ks=0): counted wait -- chunk01(t) landed, rest in flight
    asm volatile("s_waitcnt vmcnt(4)\n\ts_barrier" ::: "memory");
    HALF(t, 0, t < 15);
    // phase 2 (ks=1): counted wait -- chunk23(t) landed; tail drains fully
    if (t < 15)
      asm volatile("s_waitcnt vmcnt(4)\n\ts_barrier" ::: "memory");
    else
      asm volatile("s_waitcnt vmcnt(0)\n\ts_barrier" ::: "memory");
    HALF(t, 1, t < 15);
  }

  // epilogue (R7-verbatim): D row = (lane>>4)*4+reg, col = lane&15
#pragma unroll
  for (int mt = 0; mt < 8; ++mt) {
#pragma unroll
    for (int rr = 0; rr < 4; ++rr) {
      int ml = wm + mt * 16 + (lane >> 4) * 4 + rr;
      if (m0 + ml < count) {
        float sc = scl[ml];
        int tok = toks[ml];
        size_t ob =
            (size_t)(((tok >> 10) * 3 + r) * SS + (tok & 1023)) * HH + n0;
#pragma unroll
        for (int nt = 0; nt < 4; ++nt) {
          int nl = wn + nt * 16 + rl;
          out[ob + nl] = sc * (acc[mt][nt][rr] + bias_s[nl]);
        }
      }
    }
  }
}

extern "C" void kernel_launch(void* const* d_in, const int* in_sizes, int n_in,
                              void* d_out, int out_size, void* d_ws,
                              size_t ws_size, hipStream_t stream) {
  const float* feat = (const float*)d_in[0];  // features fp32
  const float* gw   = (const float*)d_in[1];  // gate_w fp32
  const float* ew   = (const float*)d_in[2];  // expert_w fp32
  const float* eb   = (const float*)d_in[3];  // expert_b fp32
  float* out = (float*)d_out;

  int B = in_sizes[0] / (3 * SS * HH);
  int T = B * SS;                  // tokens per branch (8192)
  int C = (T + EE - 1) / EE;       // capacity = ceil(T/E) = 2731

  // workspace layout: xb bf16 [3,T,H] | wb bf16 [9,H,H] | ints/floats (~70 MB)
  unsigned short* xbuf = (unsigned short*)d_ws;           // 3*T*HH shorts
  unsigned short* wbuf = xbuf + (size_t)3 * T * HH;       // 9*HH*HH shorts
  int* perm   = (int*)(wbuf + (size_t)9 * HH * HH);       // 9*T
  int* counts = perm + (size_t)9 * T;                     // 16 (padded)
  int* idxb   = counts + 16;                              // 3*T
  float* gv   = (float*)(idxb + (size_t)3 * T);           // 3*T
  float* scl  = gv + (size_t)3 * T;                       // 3*T

  // route (1536 blocks) + weight conversion (1152 blocks) in one launch
  k_route<<<dim3(2688), dim3(256), 0, stream>>>(feat, gw, ew, xbuf, wbuf,
                                                idxb, gv, T);
  k_scan<<<dim3(3), dim3(1024), 0, stream>>>(idxb, gv, perm, scl, counts, T, C);
  k_gemm<<<dim3(1152), dim3(512), 0, stream>>>(
      xbuf, wbuf, eb, perm, scl, counts, out, T);
}